// Round 13
// baseline (73.790 us; speedup 1.0000x reference)
//
#include <hip/hip_runtime.h>
#include <math.h>

#define S_LEN    16
#define NTOK     64     // tokens, m = s*4 + b
#define DMODEL   512
#define XB_COLS  2176   // x part (2048) + B part (128); z and C parts are dead code
#define ZX_COLS  2240   // XB_COLS + 64 dt columns
#define NCLASS   2513
#define FEATDIM  4096
#define PD_STRIDE 2516  // padded class stride (mult of 4 -> float4-aligned rows)

typedef float f4v __attribute__((ext_vector_type(4)));

// ---------------- k_fpart: in_proj partials, standard GEMM tile ------------------
// (unchanged from rounds 11/12 — conflict-free, measured-good)
__global__ __launch_bounds__(256) void k_fpart(const float* __restrict__ X,
                                               const float* __restrict__ W,
                                               float* __restrict__ partF) {
    const int tid = threadIdx.x;
    const int kf  = blockIdx.y;               // 64-k chunk
    const int jb  = blockIdx.x * 64;          // 2240 = 35*64 exact
    const int k0  = kf * 64;

    __shared__ float A[64][64];               // [k][token]
    __shared__ float B[64][64];               // [k][col]

    {
        const int t  = tid >> 2;              // 0..63 (token / col slot)
        const int kq = tid & 3;
        const int xrow = (t & 3) * 16 + (t >> 2);   // inputs row for token t
        const int e = (jb + t < XB_COLS) ? (2048 + jb + t) : (2176 + jb + t);
#pragma unroll
        for (int q = 0; q < 4; ++q) {
            const int kk = kq * 16 + q * 4;
            const float4 va = *reinterpret_cast<const float4*>(
                X + (size_t)xrow * DMODEL + k0 + kk);
            A[kk + 0][t] = va.x; A[kk + 1][t] = va.y;
            A[kk + 2][t] = va.z; A[kk + 3][t] = va.w;
            const float4 vb = *reinterpret_cast<const float4*>(
                W + (size_t)e * DMODEL + k0 + kk);
            B[kk + 0][t] = vb.x; B[kk + 1][t] = vb.y;
            B[kk + 2][t] = vb.z; B[kk + 3][t] = vb.w;
        }
    }
    __syncthreads();

    const int ti = tid >> 4;     // token quad 0..15
    const int ci = tid & 15;     // col quad 0..15
    float acc[4][4] = {{0.f}};
#pragma unroll 4
    for (int k = 0; k < 64; ++k) {
        const f4v a = *reinterpret_cast<const f4v*>(&A[k][ti * 4]);
        const f4v b = *reinterpret_cast<const f4v*>(&B[k][ci * 4]);
#pragma unroll
        for (int j = 0; j < 4; ++j)
#pragma unroll
            for (int l = 0; l < 4; ++l)
                acc[j][l] += a[j] * b[l];
    }
#pragma unroll
    for (int l = 0; l < 4; ++l) {
        f4v s; s[0] = acc[0][l]; s[1] = acc[1][l]; s[2] = acc[2][l]; s[3] = acc[3][l];
        *reinterpret_cast<f4v*>(
            partF + ((size_t)kf * ZX_COLS + jb + ci * 4 + l) * 64 + ti * 4) = s;
    }
}

// ---------------- k_fepi: reduce partials + conv/silu + dt/dA ---------------------
__global__ __launch_bounds__(256) void k_fepi(const float* __restrict__ partF, int KF,
                                              const float* __restrict__ conv_w,
                                              const float* __restrict__ conv_b,
                                              const float* __restrict__ dt_bias,
                                              const float* __restrict__ A_log,
                                              float* __restrict__ u,
                                              float* __restrict__ aArr,
                                              float* __restrict__ dArr) {
    const int lane = threadIdx.x & 63;                 // token m
    const int j    = blockIdx.x * 4 + (threadIdx.x >> 6);
    float acc = 0.f;
    for (int kf = 0; kf < KF; ++kf)
        acc += partF[((size_t)kf * ZX_COLS + j) * 64 + lane];

    if (j < XB_COLS) {
        const float4 cwv = *reinterpret_cast<const float4*>(conv_w + j * 4);
        const float cb = conv_b[j];
        float wk[4];
        wk[0] = cwv.w;                  // cw[:,0] = conv_w[:,3]
        wk[1] = wk[0] + cwv.z;
        wk[2] = wk[1] + cwv.y;
        wk[3] = wk[2] + cwv.x;
#pragma unroll
        for (int k = 0; k < 4; ++k) {
            const float v = acc * wk[k] + cb;
            u[((size_t)k * NTOK + lane) * XB_COLS + j] = v / (1.f + expf(-v));
        }
    } else {
        const int h = j - XB_COLS;
        const float x = acc + dt_bias[h];
        const float d = (x > 20.f) ? x : log1pf(expf(x));
        dArr[lane * 64 + h] = d;
        aArr[lane * 64 + h] = expf(-d * expf(A_log[h]));
    }
}

// ---------------- k_feats: collapsed SSM -> feats ROW-major [r][4096] -------------
__global__ __launch_bounds__(256) void k_feats(const float* __restrict__ u,
                                               const float* __restrict__ aArr,
                                               const float* __restrict__ dArr,
                                               float* __restrict__ feats) {
    const int t = blockIdx.x >> 2;
    const int b = blockIdx.x & 3;
    const int tid = threadIdx.x;
    const int K = 16 - t;          // unroll updates k = 0..K
    const int nvec = t + 5;        // (t+1) scan vectors + 4 unroll vectors

    __shared__ float q[16][64];
    __shared__ float cu[4][64];
    __shared__ float WV[20][32];
    __shared__ float Bv[20][128];

    if (tid < 64) {
        const int h = tid;
        const int mt = t * 4 + b;
        const float a   = aArr[mt * 64 + h];
        const float dtv = dArr[mt * 64 + h];
        float p = 1.f;
        float c3 = 0.f, c2 = 0.f, c1 = 0.f, c0 = 0.f, cs = 0.f;
        for (int j = 0; j <= K + 1; ++j) {     // p = a^j at loop head
            if (j <= K - 3) c3 += p;
            if (j == K - 2) c2 = p;
            if (j == K - 1) c1 = p;
            if (j == K)     c0 = p;
            if (j == K + 1) cs = p;
            p *= a;
        }
        cu[0][h] = dtv * c0;
        cu[1][h] = dtv * c1;
        cu[2][h] = dtv * c2;
        cu[3][h] = dtv * c3;
        float prod = 1.f;
        for (int s = t; s >= 0; --s) {
            const int ms = s * 4 + b;
            q[s][h] = cs * prod * dArr[ms * 64 + h];
            prod *= aArr[ms * 64 + h];
        }
    }
    __syncthreads();

    {   // head-reduced x vectors (32 wide each)
        const int i = tid & 31;
        const int vs = tid >> 5;
        for (int v = vs; v < nvec; v += 8) {
            float acc = 0.f;
            if (v <= t) {
                const float* base = u + (size_t)(v * 4 + b) * XB_COLS;
                for (int h = 0; h < 64; ++h) acc += q[v][h] * base[h * 32 + i];
            } else {
                const int kk = v - t - 1;
                const float* base = u + ((size_t)kk * NTOK + t * 4 + b) * XB_COLS;
                for (int h = 0; h < 64; ++h) acc += cu[kk][h] * base[h * 32 + i];
            }
            WV[v][i] = acc;
        }
    }
    for (int x = tid; x < nvec * 128; x += 256) {
        const int v = x >> 7, n = x & 127;
        size_t src;
        if (v <= t) src = (size_t)(v * 4 + b) * XB_COLS + 2048 + n;
        else        src = ((size_t)(v - t - 1) * NTOK + t * 4 + b) * XB_COLS + 2048 + n;
        Bv[v][n] = u[src];
    }
    __syncthreads();

    {   // rank-nvec outer products -> feats[r][4096] row-major
        const int i  = tid >> 3;            // headdim index 0..31
        const int n0 = (tid & 7) * 16;      // state offset
        const int r  = b * 16 + t;          // output row
        float acc[16];
#pragma unroll
        for (int nn = 0; nn < 16; ++nn) acc[nn] = 0.f;
        for (int v = 0; v < nvec; ++v) {
            const float wvv = WV[v][i];
#pragma unroll
            for (int nn = 0; nn < 16; ++nn) acc[nn] += wvv * Bv[v][n0 + nn];
        }
        float* dst = feats + (size_t)r * FEATDIM + i * 128 + n0;
#pragma unroll
        for (int qq = 0; qq < 4; ++qq) {
            float4 v4;
            v4.x = acc[qq * 4 + 0] * (1.f / 64.f);
            v4.y = acc[qq * 4 + 1] * (1.f / 64.f);
            v4.z = acc[qq * 4 + 2] * (1.f / 64.f);
            v4.w = acc[qq * 4 + 3] * (1.f / 64.f);
            *reinterpret_cast<float4*>(dst + qq * 4) = v4;
        }
    }
}

// ---------------- k_cls: classifier GEMM, 4-wave k-split blocks, micro 8x8 --------
// grid (40, KC) x 256 thr. Block tile: 64 tokens x 64 classes x (4096/KC)-k chunk.
// All 4 waves cooperatively stage each 64-k subtile (A+B = 32KB LDS); wave wv
// computes k = wv*16..+15 with private acc[8][8] and writes partial (ks*4+wv).
// Effective split-K = 4*KC; k_out sums 4*KC partials.
__global__ __launch_bounds__(256) void k_cls(const float* __restrict__ feats,
                                             const float* __restrict__ Wc,
                                             float* __restrict__ partialD) {
    const int tid   = threadIdx.x;
    const int lane  = tid & 63;
    const int wv    = tid >> 6;
    const int ks    = blockIdx.y;
    const int cls0  = blockIdx.x * 64;           // 40*64 = 2560 >= 2513
    const int chunk = FEATDIM / gridDim.y;
    const int nsub  = chunk / 64;

    __shared__ float A[64][64];                  // [k][token]
    __shared__ float B[64][64];                  // [k][class]

    const int ti = lane >> 3;                    // 0..7
    const int ci = lane & 7;                     // 0..7

    float acc[8][8] = {{0.f}};

    for (int st = 0; st < nsub; ++st) {
        const int k0 = ks * chunk + st * 64;
        __syncthreads();                         // protect A/B reuse
        {   // cooperative stage: 256 thr, 4x4 transpose into [k][x]
            const int t  = tid >> 2;             // 0..63 row slot
            const int kq = tid & 3;
            int cr = cls0 + t; if (cr > NCLASS - 1) cr = NCLASS - 1;
#pragma unroll
            for (int q = 0; q < 4; ++q) {
                const int kk = kq * 16 + q * 4;
                const float4 va = *reinterpret_cast<const float4*>(
                    feats + (size_t)t * FEATDIM + k0 + kk);
                A[kk + 0][t] = va.x; A[kk + 1][t] = va.y;
                A[kk + 2][t] = va.z; A[kk + 3][t] = va.w;
                const float4 vb = *reinterpret_cast<const float4*>(
                    Wc + (size_t)cr * FEATDIM + k0 + kk);
                B[kk + 0][t] = vb.x; B[kk + 1][t] = vb.y;
                B[kk + 2][t] = vb.z; B[kk + 3][t] = vb.w;
            }
        }
        __syncthreads();

#pragma unroll 4
        for (int k = 0; k < 16; ++k) {           // this wave's k-slice
            const int kk = wv * 16 + k;
            const f4v a0 = *reinterpret_cast<const f4v*>(&A[kk][ti * 4]);
            const f4v a1 = *reinterpret_cast<const f4v*>(&A[kk][32 + ti * 4]);
            const f4v b0 = *reinterpret_cast<const f4v*>(&B[kk][ci * 4]);
            const f4v b1 = *reinterpret_cast<const f4v*>(&B[kk][32 + ci * 4]);
#pragma unroll
            for (int j = 0; j < 4; ++j) {
#pragma unroll
                for (int l = 0; l < 4; ++l) {
                    acc[j][l]         += a0[j] * b0[l];
                    acc[j][l + 4]     += a0[j] * b1[l];
                    acc[j + 4][l]     += a1[j] * b0[l];
                    acc[j + 4][l + 4] += a1[j] * b1[l];
                }
            }
        }
    }

    const size_t obase = (size_t)(ks * 4 + wv) * (NTOK * PD_STRIDE);
#pragma unroll
    for (int ta = 0; ta < 2; ++ta) {
#pragma unroll
        for (int j = 0; j < 4; ++j) {
            const int row = ta * 32 + ti * 4 + j;
#pragma unroll
            for (int cb = 0; cb < 2; ++cb) {
                const int c = cls0 + cb * 32 + ci * 4;
                f4v s;
#pragma unroll
                for (int l = 0; l < 4; ++l) s[l] = acc[ta * 4 + j][cb * 4 + l];
                float* dst = partialD + obase + (size_t)row * PD_STRIDE + c;
                if (c + 3 < NCLASS) {
                    *reinterpret_cast<f4v*>(dst) = s;
                } else {
#pragma unroll
                    for (int l = 0; l < 4; ++l)
                        if (c + l < NCLASS) dst[l] = s[l];
                }
            }
        }
    }
}

// ---------------- k_out: reduce split-K partials + bias -> out --------------------
__global__ void k_out(const float* __restrict__ partialD, const float* __restrict__ cls_b,
                      float* __restrict__ out, int NP) {
    const int bx = blockIdx.x;                   // 640 = 64 rows * 10 c-chunks
    const int r  = bx / 10;
    const int c  = (bx % 10) * 256 + threadIdx.x;
    if (c >= NCLASS) return;
    float s = cls_b[c];
    for (int p = 0; p < NP; ++p)
        s += partialD[(size_t)p * (NTOK * PD_STRIDE) + (size_t)r * PD_STRIDE + c];
    out[(size_t)r * NCLASS + c] = s;
}

// ------------------------------------------------------------------------------
extern "C" void kernel_launch(void* const* d_in, const int* in_sizes, int n_in,
                              void* d_out, int out_size, void* d_ws, size_t ws_size,
                              hipStream_t stream) {
    const float* inputs  = (const float*)d_in[0];
    const float* in_proj = (const float*)d_in[1];
    const float* conv_w  = (const float*)d_in[2];
    const float* conv_b  = (const float*)d_in[3];
    const float* dt_bias = (const float*)d_in[4];
    const float* A_log   = (const float*)d_in[5];
    const float* cls_w   = (const float*)d_in[6];
    const float* cls_b   = (const float*)d_in[7];
    float* out = (float*)d_out;

    float* ws = (float*)d_ws;
    float* aArr    = ws;               //   4096
    float* dArr    = ws + 4096;        //   4096
    float* feats   = ws + 8192;        // 262144 (row-major [r][4096])
    float* scr     = ws + 270336;
    float* u       = scr;              // 557056 (dead after k_feats)
    float* partF   = scr + 557056;     // 8*2240*64 = 1146880 (dead after k_fepi)
    float* partialD = scr;             // (4*KC)*64*2516 (written after k_feats)

    // tiers: bytes = (270336 + max(1703936, 4*KC*161024)) * 4
    //   KC=16 (64 partials) -> 42,303,488
    //   KC=8  (32 partials) -> 21,692,416
    //   KC=4  (16 partials) -> 11,386,880 (byte-identical to round-11 proven tier)
    //   KC=2  ( 8 partials) ->  7,897,088 (proven tier)
    int KC;
    if      (ws_size >= 42303488u) KC = 16;
    else if (ws_size >= 21692416u) KC = 8;
    else if (ws_size >= 11386880u) KC = 4;
    else                           KC = 2;

    k_fpart <<<dim3(35, 8), 256, 0, stream>>>(inputs, in_proj, partF);
    k_fepi  <<<560, 256, 0, stream>>>(partF, 8, conv_w, conv_b, dt_bias, A_log,
                                      u, aArr, dArr);
    k_feats <<<64, 256, 0, stream>>>(u, aArr, dArr, feats);
    k_cls   <<<dim3(40, KC), 256, 0, stream>>>(feats, cls_w, partialD);
    k_out   <<<640, 256, 0, stream>>>(partialD, cls_b, out, 4 * KC);
}

// Round 14
// 64.550 us; speedup vs baseline: 1.1432x; 1.1432x over previous
//
#include <hip/hip_runtime.h>
#include <math.h>

#define S_LEN    16
#define NTOK     64     // tokens, m = s*4 + b
#define DMODEL   512
#define XB_COLS  2176   // x part (2048) + B part (128); z and C parts are dead code
#define ZX_COLS  2240   // XB_COLS + 64 dt columns
#define NCLASS   2513
#define FEATDIM  4096
#define PD_STRIDE 2516  // padded class stride (mult of 4 -> float4-aligned rows)

typedef float f4v __attribute__((ext_vector_type(4)));

// ---------------- k_fpart: in_proj partials, standard GEMM tile ------------------
// (unchanged from rounds 11-13 — conflict-free, measured-good)
__global__ __launch_bounds__(256) void k_fpart(const float* __restrict__ X,
                                               const float* __restrict__ W,
                                               float* __restrict__ partF) {
    const int tid = threadIdx.x;
    const int kf  = blockIdx.y;               // 64-k chunk
    const int jb  = blockIdx.x * 64;          // 2240 = 35*64 exact
    const int k0  = kf * 64;

    __shared__ float A[64][64];               // [k][token]
    __shared__ float B[64][64];               // [k][col]

    {
        const int t  = tid >> 2;              // 0..63 (token / col slot)
        const int kq = tid & 3;
        const int xrow = (t & 3) * 16 + (t >> 2);   // inputs row for token t
        const int e = (jb + t < XB_COLS) ? (2048 + jb + t) : (2176 + jb + t);
#pragma unroll
        for (int q = 0; q < 4; ++q) {
            const int kk = kq * 16 + q * 4;
            const float4 va = *reinterpret_cast<const float4*>(
                X + (size_t)xrow * DMODEL + k0 + kk);
            A[kk + 0][t] = va.x; A[kk + 1][t] = va.y;
            A[kk + 2][t] = va.z; A[kk + 3][t] = va.w;
            const float4 vb = *reinterpret_cast<const float4*>(
                W + (size_t)e * DMODEL + k0 + kk);
            B[kk + 0][t] = vb.x; B[kk + 1][t] = vb.y;
            B[kk + 2][t] = vb.z; B[kk + 3][t] = vb.w;
        }
    }
    __syncthreads();

    const int ti = tid >> 4;     // token quad 0..15
    const int ci = tid & 15;     // col quad 0..15
    float acc[4][4] = {{0.f}};
#pragma unroll 4
    for (int k = 0; k < 64; ++k) {
        const f4v a = *reinterpret_cast<const f4v*>(&A[k][ti * 4]);
        const f4v b = *reinterpret_cast<const f4v*>(&B[k][ci * 4]);
#pragma unroll
        for (int j = 0; j < 4; ++j)
#pragma unroll
            for (int l = 0; l < 4; ++l)
                acc[j][l] += a[j] * b[l];
    }
#pragma unroll
    for (int l = 0; l < 4; ++l) {
        f4v s; s[0] = acc[0][l]; s[1] = acc[1][l]; s[2] = acc[2][l]; s[3] = acc[3][l];
        *reinterpret_cast<f4v*>(
            partF + ((size_t)kf * ZX_COLS + jb + ci * 4 + l) * 64 + ti * 4) = s;
    }
}

// ---------------- k_fepi: reduce partials + conv/silu + dt/dA ---------------------
__global__ __launch_bounds__(256) void k_fepi(const float* __restrict__ partF, int KF,
                                              const float* __restrict__ conv_w,
                                              const float* __restrict__ conv_b,
                                              const float* __restrict__ dt_bias,
                                              const float* __restrict__ A_log,
                                              float* __restrict__ u,
                                              float* __restrict__ aArr,
                                              float* __restrict__ dArr) {
    const int lane = threadIdx.x & 63;                 // token m
    const int j    = blockIdx.x * 4 + (threadIdx.x >> 6);
    float acc = 0.f;
    for (int kf = 0; kf < KF; ++kf)
        acc += partF[((size_t)kf * ZX_COLS + j) * 64 + lane];

    if (j < XB_COLS) {
        const float4 cwv = *reinterpret_cast<const float4*>(conv_w + j * 4);
        const float cb = conv_b[j];
        float wk[4];
        wk[0] = cwv.w;                  // cw[:,0] = conv_w[:,3]
        wk[1] = wk[0] + cwv.z;
        wk[2] = wk[1] + cwv.y;
        wk[3] = wk[2] + cwv.x;
#pragma unroll
        for (int k = 0; k < 4; ++k) {
            const float v = acc * wk[k] + cb;
            u[((size_t)k * NTOK + lane) * XB_COLS + j] = v / (1.f + expf(-v));
        }
    } else {
        const int h = j - XB_COLS;
        const float x = acc + dt_bias[h];
        const float d = (x > 20.f) ? x : log1pf(expf(x));
        dArr[lane * 64 + h] = d;
        aArr[lane * 64 + h] = expf(-d * expf(A_log[h]));
    }
}

// ---------------- k_feats: collapsed SSM -> feats ROW-major [r][4096] -------------
__global__ __launch_bounds__(256) void k_feats(const float* __restrict__ u,
                                               const float* __restrict__ aArr,
                                               const float* __restrict__ dArr,
                                               float* __restrict__ feats) {
    const int t = blockIdx.x >> 2;
    const int b = blockIdx.x & 3;
    const int tid = threadIdx.x;
    const int K = 16 - t;          // unroll updates k = 0..K
    const int nvec = t + 5;        // (t+1) scan vectors + 4 unroll vectors

    __shared__ float q[16][64];
    __shared__ float cu[4][64];
    __shared__ float WV[20][32];
    __shared__ float Bv[20][128];

    if (tid < 64) {
        const int h = tid;
        const int mt = t * 4 + b;
        const float a   = aArr[mt * 64 + h];
        const float dtv = dArr[mt * 64 + h];
        float p = 1.f;
        float c3 = 0.f, c2 = 0.f, c1 = 0.f, c0 = 0.f, cs = 0.f;
        for (int j = 0; j <= K + 1; ++j) {     // p = a^j at loop head
            if (j <= K - 3) c3 += p;
            if (j == K - 2) c2 = p;
            if (j == K - 1) c1 = p;
            if (j == K)     c0 = p;
            if (j == K + 1) cs = p;
            p *= a;
        }
        cu[0][h] = dtv * c0;
        cu[1][h] = dtv * c1;
        cu[2][h] = dtv * c2;
        cu[3][h] = dtv * c3;
        float prod = 1.f;
        for (int s = t; s >= 0; --s) {
            const int ms = s * 4 + b;
            q[s][h] = cs * prod * dArr[ms * 64 + h];
            prod *= aArr[ms * 64 + h];
        }
    }
    __syncthreads();

    {   // head-reduced x vectors (32 wide each)
        const int i = tid & 31;
        const int vs = tid >> 5;
        for (int v = vs; v < nvec; v += 8) {
            float acc = 0.f;
            if (v <= t) {
                const float* base = u + (size_t)(v * 4 + b) * XB_COLS;
                for (int h = 0; h < 64; ++h) acc += q[v][h] * base[h * 32 + i];
            } else {
                const int kk = v - t - 1;
                const float* base = u + ((size_t)kk * NTOK + t * 4 + b) * XB_COLS;
                for (int h = 0; h < 64; ++h) acc += cu[kk][h] * base[h * 32 + i];
            }
            WV[v][i] = acc;
        }
    }
    for (int x = tid; x < nvec * 128; x += 256) {
        const int v = x >> 7, n = x & 127;
        size_t src;
        if (v <= t) src = (size_t)(v * 4 + b) * XB_COLS + 2048 + n;
        else        src = ((size_t)(v - t - 1) * NTOK + t * 4 + b) * XB_COLS + 2048 + n;
        Bv[v][n] = u[src];
    }
    __syncthreads();

    {   // rank-nvec outer products -> feats[r][4096] row-major
        const int i  = tid >> 3;            // headdim index 0..31
        const int n0 = (tid & 7) * 16;      // state offset
        const int r  = b * 16 + t;          // output row
        float acc[16];
#pragma unroll
        for (int nn = 0; nn < 16; ++nn) acc[nn] = 0.f;
        for (int v = 0; v < nvec; ++v) {
            const float wvv = WV[v][i];
#pragma unroll
            for (int nn = 0; nn < 16; ++nn) acc[nn] += wvv * Bv[v][n0 + nn];
        }
        float* dst = feats + (size_t)r * FEATDIM + i * 128 + n0;
#pragma unroll
        for (int qq = 0; qq < 4; ++qq) {
            float4 v4;
            v4.x = acc[qq * 4 + 0] * (1.f / 64.f);
            v4.y = acc[qq * 4 + 1] * (1.f / 64.f);
            v4.z = acc[qq * 4 + 2] * (1.f / 64.f);
            v4.w = acc[qq * 4 + 3] * (1.f / 64.f);
            *reinterpret_cast<float4*>(dst + qq * 4) = v4;
        }
    }
}

// ---------------- k_cls: classifier GEMM, 4-wave k-split + in-block reduce --------
// grid (40, KC) x 256 thr. Block tile: 64 tokens x 64 classes x (4096/KC)-k chunk.
// Waves cooperatively stage each 64-k subtile; wave wv computes k = wv*16..+15.
// End: waves 1-3 dump acc to LDS (lane-contiguous, conflict-free), wave 0 sums
// and writes ONE partial per block -> KC partials total (not 4*KC).
__global__ __launch_bounds__(256) void k_cls(const float* __restrict__ feats,
                                             const float* __restrict__ Wc,
                                             float* __restrict__ partialD) {
    const int tid   = threadIdx.x;
    const int lane  = tid & 63;
    const int wv    = tid >> 6;
    const int ks    = blockIdx.y;
    const int cls0  = blockIdx.x * 64;           // 40*64 = 2560 >= 2513
    const int chunk = FEATDIM / gridDim.y;
    const int nsub  = chunk / 64;

    __shared__ float lds[12288];                 // 48KB: A(16K) + B(16K) during
    float (*A)[64] = (float(*)[64])lds;          //   compute; reused as R[3][64][64]
    float (*B)[64] = (float(*)[64])(lds + 4096); //   for the cross-wave reduce.

    const int ti = lane >> 3;                    // 0..7
    const int ci = lane & 7;                     // 0..7

    float acc[8][8] = {{0.f}};

    for (int st = 0; st < nsub; ++st) {
        const int k0 = ks * chunk + st * 64;
        __syncthreads();                         // protect A/B reuse
        {   // cooperative stage: 256 thr, 4x4 transpose into [k][x]
            const int t  = tid >> 2;             // 0..63 row slot
            const int kq = tid & 3;
            int cr = cls0 + t; if (cr > NCLASS - 1) cr = NCLASS - 1;
#pragma unroll
            for (int q = 0; q < 4; ++q) {
                const int kk = kq * 16 + q * 4;
                const float4 va = *reinterpret_cast<const float4*>(
                    feats + (size_t)t * FEATDIM + k0 + kk);
                A[kk + 0][t] = va.x; A[kk + 1][t] = va.y;
                A[kk + 2][t] = va.z; A[kk + 3][t] = va.w;
                const float4 vb = *reinterpret_cast<const float4*>(
                    Wc + (size_t)cr * FEATDIM + k0 + kk);
                B[kk + 0][t] = vb.x; B[kk + 1][t] = vb.y;
                B[kk + 2][t] = vb.z; B[kk + 3][t] = vb.w;
            }
        }
        __syncthreads();

#pragma unroll
        for (int k = 0; k < 16; ++k) {           // this wave's k-slice
            const int kk = wv * 16 + k;
            const f4v a0 = *reinterpret_cast<const f4v*>(&A[kk][ti * 4]);
            const f4v a1 = *reinterpret_cast<const f4v*>(&A[kk][32 + ti * 4]);
            const f4v b0 = *reinterpret_cast<const f4v*>(&B[kk][ci * 4]);
            const f4v b1 = *reinterpret_cast<const f4v*>(&B[kk][32 + ci * 4]);
#pragma unroll
            for (int j = 0; j < 4; ++j) {
#pragma unroll
                for (int l = 0; l < 4; ++l) {
                    acc[j][l]         += a0[j] * b0[l];
                    acc[j][l + 4]     += a0[j] * b1[l];
                    acc[j + 4][l]     += a1[j] * b0[l];
                    acc[j + 4][l + 4] += a1[j] * b1[l];
                }
            }
        }
    }

    // ---- in-block cross-wave reduce: R[w][i][lane], lane-contiguous b32 ----
    __syncthreads();                             // A/B dead; lds becomes R
    if (wv > 0) {
        const int w = wv - 1;
#pragma unroll
        for (int i = 0; i < 64; ++i)
            lds[w * 4096 + i * 64 + lane] = acc[i >> 3][i & 7];
    }
    __syncthreads();
    if (wv == 0) {
#pragma unroll
        for (int i = 0; i < 64; ++i)
            acc[i >> 3][i & 7] += lds[i * 64 + lane]
                                + lds[4096 + i * 64 + lane]
                                + lds[8192 + i * 64 + lane];

        const size_t obase = (size_t)ks * (NTOK * PD_STRIDE);
#pragma unroll
        for (int ta = 0; ta < 2; ++ta) {
#pragma unroll
            for (int j = 0; j < 4; ++j) {
                const int row = ta * 32 + ti * 4 + j;
#pragma unroll
                for (int cb = 0; cb < 2; ++cb) {
                    const int c = cls0 + cb * 32 + ci * 4;
                    f4v s;
#pragma unroll
                    for (int l = 0; l < 4; ++l) s[l] = acc[ta * 4 + j][cb * 4 + l];
                    float* dst = partialD + obase + (size_t)row * PD_STRIDE + c;
                    if (c + 3 < NCLASS) {
                        *reinterpret_cast<f4v*>(dst) = s;
                    } else {
#pragma unroll
                        for (int l = 0; l < 4; ++l)
                            if (c + l < NCLASS) dst[l] = s[l];
                    }
                }
            }
        }
    }
}

// ---------------- k_out: reduce split-K partials + bias -> out --------------------
__global__ void k_out(const float* __restrict__ partialD, const float* __restrict__ cls_b,
                      float* __restrict__ out, int NP) {
    const int bx = blockIdx.x;                   // 640 = 64 rows * 10 c-chunks
    const int r  = bx / 10;
    const int c  = (bx % 10) * 256 + threadIdx.x;
    if (c >= NCLASS) return;
    float s = cls_b[c];
    for (int p = 0; p < NP; ++p)
        s += partialD[(size_t)p * (NTOK * PD_STRIDE) + (size_t)r * PD_STRIDE + c];
    out[(size_t)r * NCLASS + c] = s;
}

// ------------------------------------------------------------------------------
extern "C" void kernel_launch(void* const* d_in, const int* in_sizes, int n_in,
                              void* d_out, int out_size, void* d_ws, size_t ws_size,
                              hipStream_t stream) {
    const float* inputs  = (const float*)d_in[0];
    const float* in_proj = (const float*)d_in[1];
    const float* conv_w  = (const float*)d_in[2];
    const float* conv_b  = (const float*)d_in[3];
    const float* dt_bias = (const float*)d_in[4];
    const float* A_log   = (const float*)d_in[5];
    const float* cls_w   = (const float*)d_in[6];
    const float* cls_b   = (const float*)d_in[7];
    float* out = (float*)d_out;

    float* ws = (float*)d_ws;
    float* aArr    = ws;               //   4096
    float* dArr    = ws + 4096;        //   4096
    float* feats   = ws + 8192;        // 262144 (row-major [r][4096])
    float* scr     = ws + 270336;
    float* u       = scr;              // 557056 (dead after k_feats)
    float* partF   = scr + 557056;     // 8*2240*64 = 1146880 (dead after k_fepi)
    float* partialD = scr;             // KC*64*2516 (written after k_feats)

    // tiers: bytes = (270336 + max(1703936, KC*64*2516)) * 4
    //   KC=16 -> 11,386,880 (proven tier)   KC=8 -> 7,897,088 (proven tier)
    int KC;
    if (ws_size >= 11386880u) KC = 16;
    else                      KC = 8;

    k_fpart <<<dim3(35, 8), 256, 0, stream>>>(inputs, in_proj, partF);
    k_fepi  <<<560, 256, 0, stream>>>(partF, 8, conv_w, conv_b, dt_bias, A_log,
                                      u, aArr, dArr);
    k_feats <<<64, 256, 0, stream>>>(u, aArr, dArr, feats);
    k_cls   <<<dim3(40, KC), 256, 0, stream>>>(feats, cls_w, partialD);
    k_out   <<<640, 256, 0, stream>>>(partialD, cls_b, out, KC);
}

// Round 15
// 61.302 us; speedup vs baseline: 1.2037x; 1.0530x over previous
//
#include <hip/hip_runtime.h>
#include <math.h>

#define S_LEN    16
#define NTOK     64     // tokens, m = s*4 + b
#define DMODEL   512
#define XB_COLS  2176   // x part (2048) + B part (128); z and C parts are dead code
#define ZX_COLS  2240   // XB_COLS + 64 dt columns
#define NCLASS   2513
#define FEATDIM  4096
#define PD_STRIDE 2516  // padded class stride (mult of 4 -> float4-aligned rows)
#define APAD     68     // padded LDS row (floats): 16B-aligned, breaks write conflicts

typedef float f4v __attribute__((ext_vector_type(4)));

// ---------------- k_fpart: in_proj partials, standard GEMM tile ------------------
// Same compute as rounds 11-14; output layout flipped to partF[kf][m][j]
// (m-major) so k_fepi reads are j-contiguous per lane.
__global__ __launch_bounds__(256) void k_fpart(const float* __restrict__ X,
                                               const float* __restrict__ W,
                                               float* __restrict__ partF) {
    const int tid = threadIdx.x;
    const int kf  = blockIdx.y;               // 64-k chunk
    const int jb  = blockIdx.x * 64;          // 2240 = 35*64 exact
    const int k0  = kf * 64;

    __shared__ float A[64][64];               // [k][token]
    __shared__ float B[64][64];               // [k][col]

    {
        const int t  = tid >> 2;              // 0..63 (token / col slot)
        const int kq = tid & 3;
        const int xrow = (t & 3) * 16 + (t >> 2);   // inputs row for token t
        const int e = (jb + t < XB_COLS) ? (2048 + jb + t) : (2176 + jb + t);
#pragma unroll
        for (int q = 0; q < 4; ++q) {
            const int kk = kq * 16 + q * 4;
            const float4 va = *reinterpret_cast<const float4*>(
                X + (size_t)xrow * DMODEL + k0 + kk);
            A[kk + 0][t] = va.x; A[kk + 1][t] = va.y;
            A[kk + 2][t] = va.z; A[kk + 3][t] = va.w;
            const float4 vb = *reinterpret_cast<const float4*>(
                W + (size_t)e * DMODEL + k0 + kk);
            B[kk + 0][t] = vb.x; B[kk + 1][t] = vb.y;
            B[kk + 2][t] = vb.z; B[kk + 3][t] = vb.w;
        }
    }
    __syncthreads();

    const int ti = tid >> 4;     // token quad 0..15
    const int ci = tid & 15;     // col quad 0..15
    float acc[4][4] = {{0.f}};
#pragma unroll 4
    for (int k = 0; k < 64; ++k) {
        const f4v a = *reinterpret_cast<const f4v*>(&A[k][ti * 4]);
        const f4v b = *reinterpret_cast<const f4v*>(&B[k][ci * 4]);
#pragma unroll
        for (int j = 0; j < 4; ++j)
#pragma unroll
            for (int l = 0; l < 4; ++l)
                acc[j][l] += a[j] * b[l];
    }
#pragma unroll
    for (int jj = 0; jj < 4; ++jj) {          // token rows; cols contiguous
        f4v s; s[0] = acc[jj][0]; s[1] = acc[jj][1];
               s[2] = acc[jj][2]; s[3] = acc[jj][3];
        *reinterpret_cast<f4v*>(
            partF + ((size_t)kf * NTOK + ti * 4 + jj) * ZX_COLS + jb + ci * 4) = s;
    }
}

// ---------------- k_fepi: reduce partials + conv/silu + dt/dA ---------------------
// Flat mapping: consecutive threads = consecutive j -> partF reads AND u writes
// fully coalesced (old version scattered u stores 64-way).
__global__ __launch_bounds__(256) void k_fepi(const float* __restrict__ partF, int KF,
                                              const float* __restrict__ conv_w,
                                              const float* __restrict__ conv_b,
                                              const float* __restrict__ dt_bias,
                                              const float* __restrict__ A_log,
                                              float* __restrict__ u,
                                              float* __restrict__ aArr,
                                              float* __restrict__ dArr) {
    const int idx = blockIdx.x * 256 + threadIdx.x;   // 560*256 = 64*2240 exact
    const int m = idx / ZX_COLS;                      // token
    const int j = idx - m * ZX_COLS;                  // column
    float acc = 0.f;
    for (int kf = 0; kf < KF; ++kf)
        acc += partF[((size_t)kf * NTOK + m) * ZX_COLS + j];

    if (j < XB_COLS) {
        const float4 cwv = *reinterpret_cast<const float4*>(conv_w + j * 4);
        const float cb = conv_b[j];
        float wk[4];
        wk[0] = cwv.w;                  // cw[:,0] = conv_w[:,3]
        wk[1] = wk[0] + cwv.z;
        wk[2] = wk[1] + cwv.y;
        wk[3] = wk[2] + cwv.x;
#pragma unroll
        for (int k = 0; k < 4; ++k) {
            const float v = acc * wk[k] + cb;
            u[((size_t)k * NTOK + m) * XB_COLS + j] = v / (1.f + expf(-v));
        }
    } else {
        const int h = j - XB_COLS;
        const float x = acc + dt_bias[h];
        const float d = (x > 20.f) ? x : log1pf(expf(x));
        dArr[m * 64 + h] = d;
        aArr[m * 64 + h] = expf(-d * expf(A_log[h]));
    }
}

// ---------------- k_feats: collapsed SSM -> feats ROW-major [r][4096] -------------
__global__ __launch_bounds__(256) void k_feats(const float* __restrict__ u,
                                               const float* __restrict__ aArr,
                                               const float* __restrict__ dArr,
                                               float* __restrict__ feats) {
    const int t = blockIdx.x >> 2;
    const int b = blockIdx.x & 3;
    const int tid = threadIdx.x;
    const int K = 16 - t;          // unroll updates k = 0..K
    const int nvec = t + 5;        // (t+1) scan vectors + 4 unroll vectors

    __shared__ float q[16][64];
    __shared__ float cu[4][64];
    __shared__ float WV[20][32];
    __shared__ float Bv[20][128];

    if (tid < 64) {
        const int h = tid;
        const int mt = t * 4 + b;
        const float a   = aArr[mt * 64 + h];
        const float dtv = dArr[mt * 64 + h];
        float p = 1.f;
        float c3 = 0.f, c2 = 0.f, c1 = 0.f, c0 = 0.f, cs = 0.f;
        for (int j = 0; j <= K + 1; ++j) {     // p = a^j at loop head
            if (j <= K - 3) c3 += p;
            if (j == K - 2) c2 = p;
            if (j == K - 1) c1 = p;
            if (j == K)     c0 = p;
            if (j == K + 1) cs = p;
            p *= a;
        }
        cu[0][h] = dtv * c0;
        cu[1][h] = dtv * c1;
        cu[2][h] = dtv * c2;
        cu[3][h] = dtv * c3;
        float prod = 1.f;
        for (int s = t; s >= 0; --s) {
            const int ms = s * 4 + b;
            q[s][h] = cs * prod * dArr[ms * 64 + h];
            prod *= aArr[ms * 64 + h];
        }
    }
    __syncthreads();

    {   // head-reduced x vectors (32 wide each)
        const int i = tid & 31;
        const int vs = tid >> 5;
        for (int v = vs; v < nvec; v += 8) {
            float acc = 0.f;
            if (v <= t) {
                const float* base = u + (size_t)(v * 4 + b) * XB_COLS;
                for (int h = 0; h < 64; ++h) acc += q[v][h] * base[h * 32 + i];
            } else {
                const int kk = v - t - 1;
                const float* base = u + ((size_t)kk * NTOK + t * 4 + b) * XB_COLS;
                for (int h = 0; h < 64; ++h) acc += cu[kk][h] * base[h * 32 + i];
            }
            WV[v][i] = acc;
        }
    }
    for (int x = tid; x < nvec * 128; x += 256) {
        const int v = x >> 7, n = x & 127;
        size_t src;
        if (v <= t) src = (size_t)(v * 4 + b) * XB_COLS + 2048 + n;
        else        src = ((size_t)(v - t - 1) * NTOK + t * 4 + b) * XB_COLS + 2048 + n;
        Bv[v][n] = u[src];
    }
    __syncthreads();

    {   // rank-nvec outer products -> feats[r][4096] row-major
        const int i  = tid >> 3;            // headdim index 0..31
        const int n0 = (tid & 7) * 16;      // state offset
        const int r  = b * 16 + t;          // output row
        float acc[16];
#pragma unroll
        for (int nn = 0; nn < 16; ++nn) acc[nn] = 0.f;
        for (int v = 0; v < nvec; ++v) {
            const float wvv = WV[v][i];
#pragma unroll
            for (int nn = 0; nn < 16; ++nn) acc[nn] += wvv * Bv[v][n0 + nn];
        }
        float* dst = feats + (size_t)r * FEATDIM + i * 128 + n0;
#pragma unroll
        for (int qq = 0; qq < 4; ++qq) {
            float4 v4;
            v4.x = acc[qq * 4 + 0] * (1.f / 64.f);
            v4.y = acc[qq * 4 + 1] * (1.f / 64.f);
            v4.z = acc[qq * 4 + 2] * (1.f / 64.f);
            v4.w = acc[qq * 4 + 3] * (1.f / 64.f);
            *reinterpret_cast<float4*>(dst + qq * 4) = v4;
        }
    }
}

// ---------------- k_cls: classifier GEMM, prefetch + b128 staging + reduce --------
// grid (40, KC) x 256 thr. Tile 64t x 64c x (4096/KC)k. Per 64-k subtile:
//  - register prefetch (issued during previous compute), reg-transpose,
//    ds_write_b128 into padded [64][68] LDS (2-way write conflicts max);
//  - wave wv computes k = wv*16..+15 (micro 8x8, conflict-free b128 reads);
//  - cross-wave reduce in LDS, wave 0 writes one partial per block.
__global__ __launch_bounds__(256) void k_cls(const float* __restrict__ feats,
                                             const float* __restrict__ Wc,
                                             float* __restrict__ partialD) {
    const int tid   = threadIdx.x;
    const int lane  = tid & 63;
    const int wv    = tid >> 6;
    const int ks    = blockIdx.y;
    const int cls0  = blockIdx.x * 64;           // 40*64 = 2560 >= 2513
    const int chunk = FEATDIM / gridDim.y;
    const int nsub  = chunk / 64;

    __shared__ float lds[12288];                 // 48KB: A[64][68]+B[64][68] then R[3][4096]
    float* A = lds;                              // [k][APAD]
    float* B = lds + 64 * APAD;

    const int rq = tid >> 4;                     // staging row-quad 0..15
    const int kq = tid & 15;                     // staging k-quad 0..15 (256B coalesced)
    int crow[4];
#pragma unroll
    for (int r = 0; r < 4; ++r) {
        int cr = cls0 + rq * 4 + r; if (cr > NCLASS - 1) cr = NCLASS - 1;
        crow[r] = cr;
    }

    const int ti = lane >> 3;                    // 0..7
    const int ci = lane & 7;                     // 0..7

    float4 pa[4], pb[4];
#define LOADREGS(ST)                                                      \
    do {                                                                  \
        const int k0_ = ks * chunk + (ST) * 64 + kq * 4;                  \
        _Pragma("unroll")                                                 \
        for (int r = 0; r < 4; ++r) {                                     \
            pa[r] = *reinterpret_cast<const float4*>(                     \
                feats + (size_t)(rq * 4 + r) * FEATDIM + k0_);            \
            pb[r] = *reinterpret_cast<const float4*>(                     \
                Wc + (size_t)crow[r] * FEATDIM + k0_);                    \
        }                                                                 \
    } while (0)

    float acc[8][8] = {{0.f}};

    LOADREGS(0);
    for (int st = 0; st < nsub; ++st) {
        __syncthreads();                         // LDS free from previous compute
        {   // reg-transpose -> b128 LDS writes
#pragma unroll
            for (int s = 0; s < 4; ++s) {
                const int kk = kq * 4 + s;
                f4v wa; wa[0] = (&pa[0].x)[s]; wa[1] = (&pa[1].x)[s];
                        wa[2] = (&pa[2].x)[s]; wa[3] = (&pa[3].x)[s];
                *reinterpret_cast<f4v*>(&A[kk * APAD + rq * 4]) = wa;
                f4v wb; wb[0] = (&pb[0].x)[s]; wb[1] = (&pb[1].x)[s];
                        wb[2] = (&pb[2].x)[s]; wb[3] = (&pb[3].x)[s];
                *reinterpret_cast<f4v*>(&B[kk * APAD + rq * 4]) = wb;
            }
        }
        if (st + 1 < nsub) LOADREGS(st + 1);     // lands during compute below
        __syncthreads();                         // staging visible

#pragma unroll
        for (int k = 0; k < 16; ++k) {           // this wave's k-slice
            const int kk = wv * 16 + k;
            const f4v a0 = *reinterpret_cast<const f4v*>(&A[kk * APAD + ti * 4]);
            const f4v a1 = *reinterpret_cast<const f4v*>(&A[kk * APAD + 32 + ti * 4]);
            const f4v b0 = *reinterpret_cast<const f4v*>(&B[kk * APAD + ci * 4]);
            const f4v b1 = *reinterpret_cast<const f4v*>(&B[kk * APAD + 32 + ci * 4]);
#pragma unroll
            for (int j = 0; j < 4; ++j) {
#pragma unroll
                for (int l = 0; l < 4; ++l) {
                    acc[j][l]         += a0[j] * b0[l];
                    acc[j][l + 4]     += a0[j] * b1[l];
                    acc[j + 4][l]     += a1[j] * b0[l];
                    acc[j + 4][l + 4] += a1[j] * b1[l];
                }
            }
        }
    }
#undef LOADREGS

    // ---- in-block cross-wave reduce: R[w][i][lane], lane-contiguous b32 ----
    __syncthreads();                             // A/B dead; lds becomes R
    if (wv > 0) {
        const int w = wv - 1;
#pragma unroll
        for (int i = 0; i < 64; ++i)
            lds[w * 4096 + i * 64 + lane] = acc[i >> 3][i & 7];
    }
    __syncthreads();
    if (wv == 0) {
#pragma unroll
        for (int i = 0; i < 64; ++i)
            acc[i >> 3][i & 7] += lds[i * 64 + lane]
                                + lds[4096 + i * 64 + lane]
                                + lds[8192 + i * 64 + lane];

        const size_t obase = (size_t)ks * (NTOK * PD_STRIDE);
#pragma unroll
        for (int ta = 0; ta < 2; ++ta) {
#pragma unroll
            for (int j = 0; j < 4; ++j) {
                const int row = ta * 32 + ti * 4 + j;
#pragma unroll
                for (int cb = 0; cb < 2; ++cb) {
                    const int c = cls0 + cb * 32 + ci * 4;
                    f4v s;
#pragma unroll
                    for (int l = 0; l < 4; ++l) s[l] = acc[ta * 4 + j][cb * 4 + l];
                    float* dst = partialD + obase + (size_t)row * PD_STRIDE + c;
                    if (c + 3 < NCLASS) {
                        *reinterpret_cast<f4v*>(dst) = s;
                    } else {
#pragma unroll
                        for (int l = 0; l < 4; ++l)
                            if (c + l < NCLASS) dst[l] = s[l];
                    }
                }
            }
        }
    }
}

// ---------------- k_out: reduce split-K partials + bias -> out --------------------
__global__ void k_out(const float* __restrict__ partialD, const float* __restrict__ cls_b,
                      float* __restrict__ out, int NP) {
    const int bx = blockIdx.x;                   // 640 = 64 rows * 10 c-chunks
    const int r  = bx / 10;
    const int c  = (bx % 10) * 256 + threadIdx.x;
    if (c >= NCLASS) return;
    float s = cls_b[c];
    for (int p = 0; p < NP; ++p)
        s += partialD[(size_t)p * (NTOK * PD_STRIDE) + (size_t)r * PD_STRIDE + c];
    out[(size_t)r * NCLASS + c] = s;
}

// ------------------------------------------------------------------------------
extern "C" void kernel_launch(void* const* d_in, const int* in_sizes, int n_in,
                              void* d_out, int out_size, void* d_ws, size_t ws_size,
                              hipStream_t stream) {
    const float* inputs  = (const float*)d_in[0];
    const float* in_proj = (const float*)d_in[1];
    const float* conv_w  = (const float*)d_in[2];
    const float* conv_b  = (const float*)d_in[3];
    const float* dt_bias = (const float*)d_in[4];
    const float* A_log   = (const float*)d_in[5];
    const float* cls_w   = (const float*)d_in[6];
    const float* cls_b   = (const float*)d_in[7];
    float* out = (float*)d_out;

    float* ws = (float*)d_ws;
    float* aArr    = ws;               //   4096
    float* dArr    = ws + 4096;        //   4096
    float* feats   = ws + 8192;        // 262144 (row-major [r][4096])
    float* scr     = ws + 270336;
    float* u       = scr;              // 557056 (dead after k_feats)
    float* partF   = scr + 557056;     // 8*64*2240 = 1146880 (dead after k_fepi)
    float* partialD = scr;             // KC*64*2516 (written after k_feats)

    // tiers: bytes = (270336 + max(1703936, KC*64*2516)) * 4
    //   KC=16 -> 11,386,880 (proven tier)   KC=8 -> 7,897,088 (proven tier)
    int KC;
    if (ws_size >= 11386880u) KC = 16;
    else                      KC = 8;

    k_fpart <<<dim3(35, 8), 256, 0, stream>>>(inputs, in_proj, partF);
    k_fepi  <<<560, 256, 0, stream>>>(partF, 8, conv_w, conv_b, dt_bias, A_log,
                                      u, aArr, dArr);
    k_feats <<<64, 256, 0, stream>>>(u, aArr, dArr, feats);
    k_cls   <<<dim3(40, KC), 256, 0, stream>>>(feats, cls_w, partialD);
    k_out   <<<640, 256, 0, stream>>>(partialD, cls_b, out, KC);
}

// Round 16
// 60.227 us; speedup vs baseline: 1.2252x; 1.0179x over previous
//
#include <hip/hip_runtime.h>
#include <math.h>

#define S_LEN    16
#define NTOK     64     // tokens, m = s*4 + b
#define DMODEL   512
#define XB_COLS  2176   // x part (2048) + B part (128); z and C parts are dead code
#define ZX_COLS  2240   // XB_COLS + 64 dt columns
#define NCLASS   2513
#define FEATDIM  4096
#define PD_STRIDE 2516  // padded class stride (mult of 4 -> float4-aligned rows)
#define APAD     68     // padded LDS row (floats): 16B-aligned, breaks write conflicts

typedef float f4v __attribute__((ext_vector_type(4)));

// ---------------- k_fpart: in_proj partials, standard GEMM tile ------------------
// (unchanged from R15 — conflict-free, measured-good; partF layout [kf][m][j])
__global__ __launch_bounds__(256) void k_fpart(const float* __restrict__ X,
                                               const float* __restrict__ W,
                                               float* __restrict__ partF) {
    const int tid = threadIdx.x;
    const int kf  = blockIdx.y;               // 64-k chunk
    const int jb  = blockIdx.x * 64;          // 2240 = 35*64 exact
    const int k0  = kf * 64;

    __shared__ float A[64][64];               // [k][token]
    __shared__ float B[64][64];               // [k][col]

    {
        const int t  = tid >> 2;              // 0..63 (token / col slot)
        const int kq = tid & 3;
        const int xrow = (t & 3) * 16 + (t >> 2);   // inputs row for token t
        const int e = (jb + t < XB_COLS) ? (2048 + jb + t) : (2176 + jb + t);
#pragma unroll
        for (int q = 0; q < 4; ++q) {
            const int kk = kq * 16 + q * 4;
            const float4 va = *reinterpret_cast<const float4*>(
                X + (size_t)xrow * DMODEL + k0 + kk);
            A[kk + 0][t] = va.x; A[kk + 1][t] = va.y;
            A[kk + 2][t] = va.z; A[kk + 3][t] = va.w;
            const float4 vb = *reinterpret_cast<const float4*>(
                W + (size_t)e * DMODEL + k0 + kk);
            B[kk + 0][t] = vb.x; B[kk + 1][t] = vb.y;
            B[kk + 2][t] = vb.z; B[kk + 3][t] = vb.w;
        }
    }
    __syncthreads();

    const int ti = tid >> 4;     // token quad 0..15
    const int ci = tid & 15;     // col quad 0..15
    float acc[4][4] = {{0.f}};
#pragma unroll 4
    for (int k = 0; k < 64; ++k) {
        const f4v a = *reinterpret_cast<const f4v*>(&A[k][ti * 4]);
        const f4v b = *reinterpret_cast<const f4v*>(&B[k][ci * 4]);
#pragma unroll
        for (int j = 0; j < 4; ++j)
#pragma unroll
            for (int l = 0; l < 4; ++l)
                acc[j][l] += a[j] * b[l];
    }
#pragma unroll
    for (int jj = 0; jj < 4; ++jj) {          // token rows; cols contiguous
        f4v s; s[0] = acc[jj][0]; s[1] = acc[jj][1];
               s[2] = acc[jj][2]; s[3] = acc[jj][3];
        *reinterpret_cast<f4v*>(
            partF + ((size_t)kf * NTOK + ti * 4 + jj) * ZX_COLS + jb + ci * 4) = s;
    }
}

// ---------------- k_fepi: reduce partials + conv/silu + dt/dA, float4 I/O ---------
// 140 blocks x 256 thr; thread handles 4 consecutive j (2176 % 4 == 0 -> no
// mixed quads). All loads/stores vectorized.
__global__ __launch_bounds__(256) void k_fepi(const float* __restrict__ partF, int KF,
                                              const float* __restrict__ conv_w,
                                              const float* __restrict__ conv_b,
                                              const float* __restrict__ dt_bias,
                                              const float* __restrict__ A_log,
                                              float* __restrict__ u,
                                              float* __restrict__ aArr,
                                              float* __restrict__ dArr) {
    const int idx4 = blockIdx.x * 256 + threadIdx.x;  // 140*256 = 64*560 exact
    const int m  = idx4 / 560;                        // token
    const int j  = (idx4 - m * 560) * 4;              // first of 4 columns

    f4v acc = {0.f, 0.f, 0.f, 0.f};
    for (int kf = 0; kf < KF; ++kf)
        acc += *reinterpret_cast<const f4v*>(
            partF + ((size_t)kf * NTOK + m) * ZX_COLS + j);

    if (j < XB_COLS) {
        float wk[4][4], cb[4];
#pragma unroll
        for (int e = 0; e < 4; ++e) {
            const float4 cwv = *reinterpret_cast<const float4*>(conv_w + (j + e) * 4);
            cb[e] = conv_b[j + e];
            wk[e][0] = cwv.w;                 // cw[:,0] = conv_w[:,3]
            wk[e][1] = wk[e][0] + cwv.z;
            wk[e][2] = wk[e][1] + cwv.y;
            wk[e][3] = wk[e][2] + cwv.x;
        }
#pragma unroll
        for (int k = 0; k < 4; ++k) {
            f4v o;
#pragma unroll
            for (int e = 0; e < 4; ++e) {
                const float v = acc[e] * wk[e][k] + cb[e];
                o[e] = v / (1.f + expf(-v));
            }
            *reinterpret_cast<f4v*>(u + ((size_t)k * NTOK + m) * XB_COLS + j) = o;
        }
    } else {
        const int h = j - XB_COLS;            // multiple of 4
        f4v dv, av;
#pragma unroll
        for (int e = 0; e < 4; ++e) {
            const float x = acc[e] + dt_bias[h + e];
            const float d = (x > 20.f) ? x : log1pf(expf(x));
            dv[e] = d;
            av[e] = expf(-d * expf(A_log[h + e]));
        }
        *reinterpret_cast<f4v*>(dArr + m * 64 + h) = dv;
        *reinterpret_cast<f4v*>(aArr + m * 64 + h) = av;
    }
}

// ---------------- k_feats: collapsed SSM, i-split x4 -> 256 blocks ----------------
// block (t, b, g): handles headdim rows i = g*8 .. g*8+7 of feats[r][4096].
__global__ __launch_bounds__(256) void k_feats(const float* __restrict__ u,
                                               const float* __restrict__ aArr,
                                               const float* __restrict__ dArr,
                                               float* __restrict__ feats) {
    const int bx = blockIdx.x;          // 256 = 16 t * 4 b * 4 g
    const int g  = bx & 3;
    const int tb = bx >> 2;
    const int t  = tb >> 2;
    const int b  = tb & 3;
    const int tid = threadIdx.x;
    const int K = 16 - t;               // unroll updates k = 0..K
    const int nvec = t + 5;             // (t+1) scan vectors + 4 unroll vectors

    __shared__ float q[16][64];
    __shared__ float cu[4][64];
    __shared__ float WV[20][8];
    __shared__ float Bv[20][128];

    if (tid < 64) {
        const int h = tid;
        const int mt = t * 4 + b;
        const float a   = aArr[mt * 64 + h];
        const float dtv = dArr[mt * 64 + h];
        float p = 1.f;
        float c3 = 0.f, c2 = 0.f, c1 = 0.f, c0 = 0.f, cs = 0.f;
        for (int j = 0; j <= K + 1; ++j) {     // p = a^j at loop head
            if (j <= K - 3) c3 += p;
            if (j == K - 2) c2 = p;
            if (j == K - 1) c1 = p;
            if (j == K)     c0 = p;
            if (j == K + 1) cs = p;
            p *= a;
        }
        cu[0][h] = dtv * c0;
        cu[1][h] = dtv * c1;
        cu[2][h] = dtv * c2;
        cu[3][h] = dtv * c3;
        float prod = 1.f;
        for (int s = t; s >= 0; --s) {
            const int ms = s * 4 + b;
            q[s][h] = cs * prod * dArr[ms * 64 + h];
            prod *= aArr[ms * 64 + h];
        }
    }
    __syncthreads();

    {   // head-reduced x vectors, 8 i's per block
        const int il = tid & 7;
        const int i  = g * 8 + il;
        const int vs = tid >> 3;            // 0..31
        for (int v = vs; v < nvec; v += 32) {
            float acc = 0.f;
            if (v <= t) {
                const float* base = u + (size_t)(v * 4 + b) * XB_COLS;
                for (int h = 0; h < 64; ++h) acc += q[v][h] * base[h * 32 + i];
            } else {
                const int kk = v - t - 1;
                const float* base = u + ((size_t)kk * NTOK + t * 4 + b) * XB_COLS;
                for (int h = 0; h < 64; ++h) acc += cu[kk][h] * base[h * 32 + i];
            }
            WV[v][il] = acc;
        }
    }
    for (int x = tid; x < nvec * 128; x += 256) {
        const int v = x >> 7, n = x & 127;
        size_t src;
        if (v <= t) src = (size_t)(v * 4 + b) * XB_COLS + 2048 + n;
        else        src = ((size_t)(v - t - 1) * NTOK + t * 4 + b) * XB_COLS + 2048 + n;
        Bv[v][n] = u[src];
    }
    __syncthreads();

    {   // rank-nvec outer products for this block's 8x128 slice
        const int il = tid >> 5;            // 0..7
        const int i  = g * 8 + il;
        const int n0 = (tid & 31) * 4;
        const int r  = b * 16 + t;          // output row
        float acc[4] = {0.f, 0.f, 0.f, 0.f};
        for (int v = 0; v < nvec; ++v) {
            const float wvv = WV[v][il];
#pragma unroll
            for (int nn = 0; nn < 4; ++nn) acc[nn] += wvv * Bv[v][n0 + nn];
        }
        f4v o;
#pragma unroll
        for (int nn = 0; nn < 4; ++nn) o[nn] = acc[nn] * (1.f / 64.f);
        *reinterpret_cast<f4v*>(feats + (size_t)r * FEATDIM + i * 128 + n0) = o;
    }
}

// ---------------- k_cls: classifier GEMM, prefetch + b128 staging -----------------
// grid (40, KC) x 256 thr. Tile 64t x 64c x (4096/KC)k, 4-wave k-split,
// micro 8x8. NEW: parallel 2-phase cross-wave reduce (all waves dump + reduce).
__global__ __launch_bounds__(256) void k_cls(const float* __restrict__ feats,
                                             const float* __restrict__ Wc,
                                             float* __restrict__ partialD) {
    const int tid   = threadIdx.x;
    const int lane  = tid & 63;
    const int wv    = tid >> 6;
    const int ks    = blockIdx.y;
    const int cls0  = blockIdx.x * 64;           // 40*64 = 2560 >= 2513
    const int chunk = FEATDIM / gridDim.y;
    const int nsub  = chunk / 64;

    __shared__ float lds[12288];                 // 48KB: A[64][68]+B[64][68], then R
    float* A = lds;                              // [k][APAD]
    float* B = lds + 64 * APAD;

    const int rq = tid >> 4;                     // staging row-quad 0..15
    const int kq = tid & 15;                     // staging k-quad 0..15
    int crow[4];
#pragma unroll
    for (int r = 0; r < 4; ++r) {
        int cr = cls0 + rq * 4 + r; if (cr > NCLASS - 1) cr = NCLASS - 1;
        crow[r] = cr;
    }

    const int ti = lane >> 3;                    // 0..7
    const int ci = lane & 7;                     // 0..7

    float4 pa[4], pb[4];
#define LOADREGS(ST)                                                      \
    do {                                                                  \
        const int k0_ = ks * chunk + (ST) * 64 + kq * 4;                  \
        _Pragma("unroll")                                                 \
        for (int r = 0; r < 4; ++r) {                                     \
            pa[r] = *reinterpret_cast<const float4*>(                     \
                feats + (size_t)(rq * 4 + r) * FEATDIM + k0_);            \
            pb[r] = *reinterpret_cast<const float4*>(                     \
                Wc + (size_t)crow[r] * FEATDIM + k0_);                    \
        }                                                                 \
    } while (0)

    float acc[8][8] = {{0.f}};

    LOADREGS(0);
    for (int st = 0; st < nsub; ++st) {
        __syncthreads();                         // LDS free from previous compute
        {   // reg-transpose -> b128 LDS writes
#pragma unroll
            for (int s = 0; s < 4; ++s) {
                const int kk = kq * 4 + s;
                f4v wa; wa[0] = (&pa[0].x)[s]; wa[1] = (&pa[1].x)[s];
                        wa[2] = (&pa[2].x)[s]; wa[3] = (&pa[3].x)[s];
                *reinterpret_cast<f4v*>(&A[kk * APAD + rq * 4]) = wa;
                f4v wb; wb[0] = (&pb[0].x)[s]; wb[1] = (&pb[1].x)[s];
                        wb[2] = (&pb[2].x)[s]; wb[3] = (&pb[3].x)[s];
                *reinterpret_cast<f4v*>(&B[kk * APAD + rq * 4]) = wb;
            }
        }
        if (st + 1 < nsub) LOADREGS(st + 1);     // lands during compute below
        __syncthreads();                         // staging visible

#pragma unroll
        for (int k = 0; k < 16; ++k) {           // this wave's k-slice
            const int kk = wv * 16 + k;
            const f4v a0 = *reinterpret_cast<const f4v*>(&A[kk * APAD + ti * 4]);
            const f4v a1 = *reinterpret_cast<const f4v*>(&A[kk * APAD + 32 + ti * 4]);
            const f4v b0 = *reinterpret_cast<const f4v*>(&B[kk * APAD + ci * 4]);
            const f4v b1 = *reinterpret_cast<const f4v*>(&B[kk * APAD + 32 + ci * 4]);
#pragma unroll
            for (int j = 0; j < 4; ++j) {
#pragma unroll
                for (int l = 0; l < 4; ++l) {
                    acc[j][l]         += a0[j] * b0[l];
                    acc[j][l + 4]     += a0[j] * b1[l];
                    acc[j + 4][l]     += a1[j] * b0[l];
                    acc[j + 4][l + 4] += a1[j] * b1[l];
                }
            }
        }
    }
#undef LOADREGS

    // ---- parallel cross-wave reduce, two 32KB phases; wave w owns acc-row w ----
    const size_t obase = (size_t)ks * (NTOK * PD_STRIDE);
#pragma unroll
    for (int half = 0; half < 2; ++half) {
        __syncthreads();                         // A/B (or prev half's R) dead
#pragma unroll
        for (int i = 0; i < 32; ++i)             // dump [wv][i][lane], lane-contig
            lds[wv * 2048 + i * 64 + lane] = acc[half * 4 + (i >> 3)][i & 7];
        __syncthreads();

        float s[8];
#pragma unroll
        for (int l = 0; l < 8; ++l)
            s[l] = lds[          (wv * 8 + l) * 64 + lane]
                 + lds[2048 +    (wv * 8 + l) * 64 + lane]
                 + lds[4096 +    (wv * 8 + l) * 64 + lane]
                 + lds[6144 +    (wv * 8 + l) * 64 + lane];

        const int row = half * 32 + ti * 4 + wv;
#pragma unroll
        for (int cb = 0; cb < 2; ++cb) {
            const int c = cls0 + cb * 32 + ci * 4;
            f4v v4;
#pragma unroll
            for (int l = 0; l < 4; ++l) v4[l] = s[cb * 4 + l];
            float* dst = partialD + obase + (size_t)row * PD_STRIDE + c;
            if (c + 3 < NCLASS) {
                *reinterpret_cast<f4v*>(dst) = v4;
            } else {
#pragma unroll
                for (int l = 0; l < 4; ++l)
                    if (c + l < NCLASS) dst[l] = v4[l];
            }
        }
    }
}

// ---------------- k_out: reduce split-K partials + bias -> out --------------------
__global__ void k_out(const float* __restrict__ partialD, const float* __restrict__ cls_b,
                      float* __restrict__ out, int NP) {
    const int bx = blockIdx.x;                   // 640 = 64 rows * 10 c-chunks
    const int r  = bx / 10;
    const int c  = (bx % 10) * 256 + threadIdx.x;
    if (c >= NCLASS) return;
    float s = cls_b[c];
    for (int p = 0; p < NP; ++p)
        s += partialD[(size_t)p * (NTOK * PD_STRIDE) + (size_t)r * PD_STRIDE + c];
    out[(size_t)r * NCLASS + c] = s;
}

// ------------------------------------------------------------------------------
extern "C" void kernel_launch(void* const* d_in, const int* in_sizes, int n_in,
                              void* d_out, int out_size, void* d_ws, size_t ws_size,
                              hipStream_t stream) {
    const float* inputs  = (const float*)d_in[0];
    const float* in_proj = (const float*)d_in[1];
    const float* conv_w  = (const float*)d_in[2];
    const float* conv_b  = (const float*)d_in[3];
    const float* dt_bias = (const float*)d_in[4];
    const float* A_log   = (const float*)d_in[5];
    const float* cls_w   = (const float*)d_in[6];
    const float* cls_b   = (const float*)d_in[7];
    float* out = (float*)d_out;

    float* ws = (float*)d_ws;
    float* aArr    = ws;               //   4096
    float* dArr    = ws + 4096;        //   4096
    float* feats   = ws + 8192;        // 262144 (row-major [r][4096])
    float* scr     = ws + 270336;
    float* u       = scr;              // 557056 (dead after k_feats)
    float* partF   = scr + 557056;     // 8*64*2240 = 1146880 (dead after k_fepi)
    float* partialD = scr;             // KC*64*2516 (written after k_feats)

    // tiers: bytes = (270336 + max(1703936, KC*64*2516)) * 4
    //   KC=16 -> 11,386,880 (proven tier)   KC=8 -> 7,897,088 (proven tier)
    int KC;
    if (ws_size >= 11386880u) KC = 16;
    else                      KC = 8;

    k_fpart <<<dim3(35, 8), 256, 0, stream>>>(inputs, in_proj, partF);
    k_fepi  <<<140, 256, 0, stream>>>(partF, 8, conv_w, conv_b, dt_bias, A_log,
                                      u, aArr, dArr);
    k_feats <<<256, 256, 0, stream>>>(u, aArr, dArr, feats);
    k_cls   <<<dim3(40, KC), 256, 0, stream>>>(feats, cls_w, partialD);
    k_out   <<<640, 256, 0, stream>>>(partialD, cls_b, out, KC);
}